// Round 1
// baseline (4506.263 us; speedup 1.0000x reference)
//
#include <hip/hip_runtime.h>
#include <cstdint>
#include <cstddef>

#define S_LEN 2048
#define BATCH 64
#define ISZ   256
#define HSZ   128

// ---------------------------------------------------------------------------
// GEMM: C = A(MxK) @ W(NxK)^T (+bias)
// LAYOUT 0: C[m*N + n]   (row-major M x N)
// LAYOUT 1: C[(m/64)*N*64 + n*64 + (m%64)]   -> (s, c, b) transposed store
// ---------------------------------------------------------------------------
template<int LAYOUT>
__global__ __launch_bounds__(256)
void gemm_nt(const float* __restrict__ A, const float* __restrict__ W,
             const float* __restrict__ bias, float* __restrict__ C,
             int M, int N, int K)
{
    __shared__ float As[64][65];   // pad 65: A-reads 2-way conflict max
    __shared__ float Bs[64][68];   // pad 68: float4-aligned reads along n
    const int tid = threadIdx.x;
    const int tc = tid & 15, tr = tid >> 4;
    const int m0 = blockIdx.y * 64;
    const int n0 = blockIdx.x * 64;

    float acc[4][4] = {};

    for (int k0 = 0; k0 < K; k0 += 64) {
        // stage A tile (64 rows x 64 k), coalesced float4
        #pragma unroll
        for (int it = 0; it < 4; ++it) {
            int idx = tid + it * 256;
            int r = idx >> 4, c4 = (idx & 15) * 4;
            const float4 v = *reinterpret_cast<const float4*>(
                &A[(size_t)(m0 + r) * K + k0 + c4]);
            As[r][c4+0] = v.x; As[r][c4+1] = v.y;
            As[r][c4+2] = v.z; As[r][c4+3] = v.w;
        }
        // stage W tile transposed: Bs[k][n] = W[n0+n][k0+k]
        #pragma unroll
        for (int it = 0; it < 4; ++it) {
            int idx = tid + it * 256;
            int n = idx >> 4, k4 = (idx & 15) * 4;
            const float4 v = *reinterpret_cast<const float4*>(
                &W[(size_t)(n0 + n) * K + k0 + k4]);
            Bs[k4+0][n] = v.x; Bs[k4+1][n] = v.y;
            Bs[k4+2][n] = v.z; Bs[k4+3][n] = v.w;
        }
        __syncthreads();

        #pragma unroll
        for (int kk = 0; kk < 64; ++kk) {
            float a0 = As[tr*4+0][kk];
            float a1 = As[tr*4+1][kk];
            float a2 = As[tr*4+2][kk];
            float a3 = As[tr*4+3][kk];
            float4 b = *reinterpret_cast<const float4*>(&Bs[kk][tc*4]);
            acc[0][0] += a0*b.x; acc[0][1] += a0*b.y; acc[0][2] += a0*b.z; acc[0][3] += a0*b.w;
            acc[1][0] += a1*b.x; acc[1][1] += a1*b.y; acc[1][2] += a1*b.z; acc[1][3] += a1*b.w;
            acc[2][0] += a2*b.x; acc[2][1] += a2*b.y; acc[2][2] += a2*b.z; acc[2][3] += a2*b.w;
            acc[3][0] += a3*b.x; acc[3][1] += a3*b.y; acc[3][2] += a3*b.z; acc[3][3] += a3*b.w;
        }
        __syncthreads();
    }

    float bv[4];
    #pragma unroll
    for (int j = 0; j < 4; ++j)
        bv[j] = bias ? bias[n0 + tc*4 + j] : 0.f;

    #pragma unroll
    for (int i = 0; i < 4; ++i) {
        #pragma unroll
        for (int j = 0; j < 4; ++j) {
            float v = acc[i][j] + bv[j];
            int m = m0 + tr*4 + i;
            int n = n0 + tc*4 + j;
            if (LAYOUT == 0)
                C[(size_t)m * N + n] = v;
            else
                C[(size_t)(m >> 6) * ((size_t)N * 64) + (size_t)n * 64 + (m & 63)] = v;
        }
    }
}

// ---------------------------------------------------------------------------
// GRU recurrence: one workgroup per (direction, batch). 384 threads.
// Thread j owns gate row j of W_hh (128 floats in VGPRs); h broadcast via LDS.
// ---------------------------------------------------------------------------
__global__ __launch_bounds__(384)
void gru_scan(const float* __restrict__ xg_f, const float* __restrict__ xg_b,
              const float* __restrict__ whh_f, const float* __restrict__ whh_b,
              const float* __restrict__ bhh_f, const float* __restrict__ bhh_b,
              const float* __restrict__ h0,     // (2,64,128)
              float* __restrict__ outs,         // (S,64,256)
              float* __restrict__ hid_out)      // (2,64,128)
{
    const int j   = threadIdx.x;        // 0..383 (gate row)
    const int dir = blockIdx.x >> 6;
    const int b   = blockIdx.x & 63;

    const float* xg  = dir ? xg_b  : xg_f;
    const float* whh = dir ? whh_b : whh_f;
    const float* bhh = dir ? bhh_b : bhh_f;

    float w[128];
    #pragma unroll
    for (int k4 = 0; k4 < 32; ++k4) {
        float4 v = *reinterpret_cast<const float4*>(&whh[(size_t)j * 128 + k4 * 4]);
        w[k4*4+0] = v.x; w[k4*4+1] = v.y; w[k4*4+2] = v.z; w[k4*4+3] = v.w;
    }
    const float bh = bhh[j];

    __shared__ float hs[128];
    __shared__ float ghs[384];
    if (j < 128) hs[j] = h0[dir * (64*128) + b * 128 + j];
    __syncthreads();

    for (int t = 0; t < S_LEN; ++t) {
        const int s = dir ? (S_LEN - 1 - t) : t;
        const float* xrow = xg + ((size_t)s * 64 + b) * 384;

        // hoist global loads above the dot product to hide HBM latency
        float xr = 0.f, xz = 0.f, xn = 0.f;
        if (j < 128) { xr = xrow[j]; xz = xrow[j + 128]; xn = xrow[j + 256]; }

        float a0 = 0.f, a1 = 0.f, a2 = 0.f, a3 = 0.f;
        #pragma unroll
        for (int k4 = 0; k4 < 32; ++k4) {
            float4 h4 = *reinterpret_cast<const float4*>(&hs[k4 * 4]); // broadcast
            a0 += w[k4*4+0] * h4.x; a1 += w[k4*4+1] * h4.y;
            a2 += w[k4*4+2] * h4.z; a3 += w[k4*4+3] * h4.w;
        }
        ghs[j] = (a0 + a1) + (a2 + a3) + bh;
        __syncthreads();

        if (j < 128) {
            float hr = ghs[j], hz = ghs[j + 128], hn = ghs[j + 256];
            float r = 1.f / (1.f + __expf(-(xr + hr)));
            float z = 1.f / (1.f + __expf(-(xz + hz)));
            float n = tanhf(xn + r * hn);
            float hnew = (1.f - z) * n + z * hs[j];
            hs[j] = hnew;
            outs[((size_t)s * 64 + b) * 256 + dir * 128 + j] = hnew;
        }
        __syncthreads();
    }
    if (j < 128) hid_out[dir * (64*128) + b * 128 + j] = hs[j];
}

// ---------------------------------------------------------------------------
// Batch-axis softmax (over b, 64 lanes = one wave) + weighted partial
// reduction over a 32-step s-chunk.  logits are in (S, C, B) layout.
// ---------------------------------------------------------------------------
__global__ __launch_bounds__(256)
void attn_reduce(const float* __restrict__ lt,    // (S,256,64)
                 const float* __restrict__ outs,  // (S,64,256)
                 float* __restrict__ part)        // (64 chunks,64 b,256 c)
{
    __shared__ float ltile[64 * 64];     // [c_local][b]
    __shared__ float otile[64 * 65];     // [b][c_local] padded

    const int tid  = threadIdx.x;
    const int lane = tid & 63;           // = b
    const int wv   = tid >> 6;           // wave 0..3
    const int c0   = blockIdx.x * 64;    // channel block
    const int sc   = blockIdx.y;         // s-chunk 0..63

    float acc[16];
    #pragma unroll
    for (int i = 0; i < 16; ++i) acc[i] = 0.f;

    for (int si = 0; si < 32; ++si) {
        const int s = sc * 32 + si;

        // logits tile: 4096 contiguous floats
        const float4* src = reinterpret_cast<const float4*>(
            lt + (size_t)s * 16384 + (size_t)c0 * 64);
        #pragma unroll
        for (int i = 0; i < 4; ++i)
            reinterpret_cast<float4*>(ltile)[tid + i * 256] = src[tid + i * 256];

        // out_state tile (64 b x 64 c), coalesced along c
        #pragma unroll
        for (int i = 0; i < 4; ++i) {
            int idx = tid + i * 256;
            int bb = idx >> 4, c4 = (idx & 15) * 4;
            float4 v = *reinterpret_cast<const float4*>(
                &outs[((size_t)s * 64 + bb) * 256 + c0 + c4]);
            otile[bb*65 + c4+0] = v.x; otile[bb*65 + c4+1] = v.y;
            otile[bb*65 + c4+2] = v.z; otile[bb*65 + c4+3] = v.w;
        }
        __syncthreads();

        #pragma unroll
        for (int ci = 0; ci < 16; ++ci) {
            int c = wv * 16 + ci;
            float x = ltile[c * 64 + lane];
            float m = x;
            #pragma unroll
            for (int off = 32; off; off >>= 1)
                m = fmaxf(m, __shfl_xor(m, off));
            float e = __expf(x - m);
            float ssum = e;
            #pragma unroll
            for (int off = 32; off; off >>= 1)
                ssum += __shfl_xor(ssum, off);
            float attn = e / ssum;
            acc[ci] += attn * otile[lane * 65 + c];
        }
        __syncthreads();
    }

    #pragma unroll
    for (int ci = 0; ci < 16; ++ci) {
        int c = wv * 16 + ci;
        part[(size_t)sc * 16384 + (size_t)lane * 256 + c0 + c] = acc[ci];
    }
}

__global__ __launch_bounds__(256)
void reduce_part(const float* __restrict__ part, float* __restrict__ sent)
{
    int idx = blockIdx.x * 256 + threadIdx.x;   // 0..16383 = b*256+c
    float s = 0.f;
    for (int sc = 0; sc < 64; ++sc)
        s += part[(size_t)sc * 16384 + idx];
    sent[idx] = s;
}

// ---------------------------------------------------------------------------
extern "C" void kernel_launch(void* const* d_in, const int* in_sizes, int n_in,
                              void* d_out, int out_size, void* d_ws, size_t ws_size,
                              hipStream_t stream)
{
    const float* inp    = (const float*)d_in[0];
    const float* hid0   = (const float*)d_in[1];
    const float* w_ih_f = (const float*)d_in[2];
    const float* w_hh_f = (const float*)d_in[3];
    const float* b_ih_f = (const float*)d_in[4];
    const float* b_hh_f = (const float*)d_in[5];
    const float* w_ih_b = (const float*)d_in[6];
    const float* w_hh_b = (const float*)d_in[7];
    const float* b_ih_b = (const float*)d_in[8];
    const float* b_hh_b = (const float*)d_in[9];
    const float* attn_w = (const float*)d_in[10];
    const float* attn_b = (const float*)d_in[11];
    const float* comb_w = (const float*)d_in[12];

    float* out = (float*)d_out;   // [0,16384): sent, [16384,32768): hid_out

    char* ws = (char*)d_ws;
    const size_t XG_BYTES = (size_t)S_LEN * BATCH * 384 * 4;  // 201,326,592
    const size_t OS_BYTES = (size_t)S_LEN * BATCH * 256 * 4;  // 134,217,728
    if (ws_size < 2 * XG_BYTES + OS_BYTES) return;  // need 512 MiB scratch

    float* xg_f   = (float*)(ws);
    float* xg_b   = (float*)(ws + XG_BYTES);
    float* outs   = (float*)(ws + 2 * XG_BYTES);
    float* sa     = (float*)(ws);               // reuse xg_f (dead after scan)
    float* logits = (float*)(ws + XG_BYTES);    // reuse xg_b
    float* part   = (float*)(ws);               // reuse sa (dead after K4)

    const int M = S_LEN * BATCH;                // 131072
    dim3 blk(256);

    // K1: input-side gates, both directions
    gemm_nt<0><<<dim3(6, 2048), blk, 0, stream>>>(inp, w_ih_f, b_ih_f, xg_f, M, 384, 256);
    gemm_nt<0><<<dim3(6, 2048), blk, 0, stream>>>(inp, w_ih_b, b_ih_b, xg_b, M, 384, 256);

    // K2: sequential bidirectional GRU (128 independent WGs)
    gru_scan<<<dim3(128), dim3(384), 0, stream>>>(
        xg_f, xg_b, w_hh_f, w_hh_b, b_hh_f, b_hh_b, hid0, outs, out + 16384);

    // K3: sent_annotation = out_state @ attn_w^T + attn_b
    gemm_nt<0><<<dim3(4, 2048), blk, 0, stream>>>(outs, attn_w, attn_b, sa, M, 256, 256);

    // K4: logits = sa @ comb_w^T, stored transposed (S,C,B)
    gemm_nt<1><<<dim3(4, 2048), blk, 0, stream>>>(sa, comb_w, nullptr, logits, M, 256, 256);

    // K5: softmax over batch + weighted partial sum over s-chunks
    attn_reduce<<<dim3(4, 64), blk, 0, stream>>>(logits, outs, part);

    // K6: final reduction over s-chunks -> sent
    reduce_part<<<dim3(64), blk, 0, stream>>>(part, out);
}

// Round 2
// 4413.840 us; speedup vs baseline: 1.0209x; 1.0209x over previous
//
#include <hip/hip_runtime.h>
#include <cstdint>
#include <cstddef>

#define S_LEN 2048
#define BATCH 64
#define ISZ   256
#define HSZ   128

// ---------------------------------------------------------------------------
// GEMM: C = A(MxK) @ W(NxK)^T (+bias)
// LAYOUT 0: C[m*N + n]   (row-major M x N)
// LAYOUT 1: C[(m/64)*N*64 + n*64 + (m%64)]   -> (s, c, b) transposed store
// ---------------------------------------------------------------------------
template<int LAYOUT>
__global__ __launch_bounds__(256)
void gemm_nt(const float* __restrict__ A, const float* __restrict__ W,
             const float* __restrict__ bias, float* __restrict__ C,
             int M, int N, int K)
{
    __shared__ float As[64][65];   // pad 65: A-reads 2-way conflict max
    __shared__ float Bs[64][68];   // pad 68: float4-aligned reads along n
    const int tid = threadIdx.x;
    const int tc = tid & 15, tr = tid >> 4;
    const int m0 = blockIdx.y * 64;
    const int n0 = blockIdx.x * 64;

    float acc[4][4] = {};

    for (int k0 = 0; k0 < K; k0 += 64) {
        // stage A tile (64 rows x 64 k), coalesced float4
        #pragma unroll
        for (int it = 0; it < 4; ++it) {
            int idx = tid + it * 256;
            int r = idx >> 4, c4 = (idx & 15) * 4;
            const float4 v = *reinterpret_cast<const float4*>(
                &A[(size_t)(m0 + r) * K + k0 + c4]);
            As[r][c4+0] = v.x; As[r][c4+1] = v.y;
            As[r][c4+2] = v.z; As[r][c4+3] = v.w;
        }
        // stage W tile transposed: Bs[k][n] = W[n0+n][k0+k]
        #pragma unroll
        for (int it = 0; it < 4; ++it) {
            int idx = tid + it * 256;
            int n = idx >> 4, k4 = (idx & 15) * 4;
            const float4 v = *reinterpret_cast<const float4*>(
                &W[(size_t)(n0 + n) * K + k0 + k4]);
            Bs[k4+0][n] = v.x; Bs[k4+1][n] = v.y;
            Bs[k4+2][n] = v.z; Bs[k4+3][n] = v.w;
        }
        __syncthreads();

        #pragma unroll
        for (int kk = 0; kk < 64; ++kk) {
            float a0 = As[tr*4+0][kk];
            float a1 = As[tr*4+1][kk];
            float a2 = As[tr*4+2][kk];
            float a3 = As[tr*4+3][kk];
            float4 b = *reinterpret_cast<const float4*>(&Bs[kk][tc*4]);
            acc[0][0] += a0*b.x; acc[0][1] += a0*b.y; acc[0][2] += a0*b.z; acc[0][3] += a0*b.w;
            acc[1][0] += a1*b.x; acc[1][1] += a1*b.y; acc[1][2] += a1*b.z; acc[1][3] += a1*b.w;
            acc[2][0] += a2*b.x; acc[2][1] += a2*b.y; acc[2][2] += a2*b.z; acc[2][3] += a2*b.w;
            acc[3][0] += a3*b.x; acc[3][1] += a3*b.y; acc[3][2] += a3*b.z; acc[3][3] += a3*b.w;
        }
        __syncthreads();
    }

    float bv[4];
    #pragma unroll
    for (int j = 0; j < 4; ++j)
        bv[j] = bias ? bias[n0 + tc*4 + j] : 0.f;

    #pragma unroll
    for (int i = 0; i < 4; ++i) {
        #pragma unroll
        for (int j = 0; j < 4; ++j) {
            float v = acc[i][j] + bv[j];
            int m = m0 + tr*4 + i;
            int n = n0 + tc*4 + j;
            if (LAYOUT == 0)
                C[(size_t)m * N + n] = v;
            else
                C[(size_t)(m >> 6) * ((size_t)N * 64) + (size_t)n * 64 + (m & 63)] = v;
        }
    }
}

// ---------------------------------------------------------------------------
// GRU recurrence: one workgroup per (direction, batch). 384 threads.
// Thread j owns gate row j of W_hh (32 float4 = 128 VGPRs, forced resident
// via __launch_bounds__(384,2) -> 256-VGPR cap); h broadcast via LDS.
// Raw s_barrier + lgkmcnt(0) (NOT __syncthreads) so the x(t+1) prefetch
// global loads stay in flight across barriers.
// ---------------------------------------------------------------------------
__global__ __launch_bounds__(384, 2)
void gru_scan(const float* __restrict__ xg_f, const float* __restrict__ xg_b,
              const float* __restrict__ whh_f, const float* __restrict__ whh_b,
              const float* __restrict__ bhh_f, const float* __restrict__ bhh_b,
              const float* __restrict__ h0,     // (2,64,128)
              float* __restrict__ outs,         // (S,64,256)
              float* __restrict__ hid_out)      // (2,64,128)
{
    const int j   = threadIdx.x;        // 0..383 (gate row)
    const int dir = blockIdx.x >> 6;
    const int b   = blockIdx.x & 63;

    const float* xg  = dir ? xg_b  : xg_f;
    const float* whh = dir ? whh_b : whh_f;
    const float* bhh = dir ? bhh_b : bhh_f;

    float4 w[32];
    #pragma unroll
    for (int k4 = 0; k4 < 32; ++k4)
        w[k4] = *reinterpret_cast<const float4*>(&whh[(size_t)j * 128 + k4 * 4]);
    const float bh = bhh[j];

    __shared__ float hs[128];
    __shared__ float ghs[384];

    float hj = 0.f;
    if (j < 128) {
        hj = h0[dir * (64*128) + b * 128 + j];
        hs[j] = hj;
    }

    // prefetch x gates for t=0
    float xr = 0.f, xz = 0.f, xn = 0.f;
    {
        const int s0 = dir ? (S_LEN - 1) : 0;
        const float* xrow = xg + ((size_t)s0 * 64 + b) * 384;
        if (j < 128) { xr = xrow[j]; xz = xrow[j + 128]; xn = xrow[j + 256]; }
    }
    asm volatile("s_waitcnt lgkmcnt(0)" ::: "memory");
    __builtin_amdgcn_s_barrier();

    for (int t = 0; t < S_LEN; ++t) {
        // issue x(t+1) prefetch FIRST: ~matvec+barrier+activation of slack
        // before the value is needed (vmcnt not drained at raw barriers)
        float pxr = 0.f, pxz = 0.f, pxn = 0.f;
        if (t + 1 < S_LEN && j < 128) {
            const int s1 = dir ? (S_LEN - 2 - t) : (t + 1);
            const float* xrow = xg + ((size_t)s1 * 64 + b) * 384;
            pxr = xrow[j]; pxz = xrow[j + 128]; pxn = xrow[j + 256];
        }

        // matvec: ghs[j] = W_hh[j,:] . h + bhh[j]
        float a0 = 0.f, a1 = 0.f, a2 = 0.f, a3 = 0.f;
        #pragma unroll
        for (int k4 = 0; k4 < 32; ++k4) {
            const float4 h4 = *reinterpret_cast<const float4*>(&hs[k4 * 4]); // broadcast
            a0 = fmaf(w[k4].x, h4.x, a0);
            a1 = fmaf(w[k4].y, h4.y, a1);
            a2 = fmaf(w[k4].z, h4.z, a2);
            a3 = fmaf(w[k4].w, h4.w, a3);
        }
        ghs[j] = (a0 + a1) + (a2 + a3) + bh;

        asm volatile("s_waitcnt lgkmcnt(0)" ::: "memory");
        __builtin_amdgcn_s_barrier();

        if (j < 128) {
            const float hr = ghs[j], hz = ghs[j + 128], hn = ghs[j + 256];
            const float r = 1.f / (1.f + __expf(-(xr + hr)));
            const float z = 1.f / (1.f + __expf(-(xz + hz)));
            const float x2 = xn + r * hn;
            const float ax = fabsf(x2);
            const float e  = __expf(-2.f * ax);
            const float n  = copysignf((1.f - e) / (1.f + e), x2);  // tanh
            const float hnew = n + z * (hj - n);   // (1-z)*n + z*h
            hj = hnew;
            hs[j] = hnew;
            const int s = dir ? (S_LEN - 1 - t) : t;
            outs[((size_t)s * 64 + b) * 256 + dir * 128 + j] = hnew;
            xr = pxr; xz = pxz; xn = pxn;
        }

        asm volatile("s_waitcnt lgkmcnt(0)" ::: "memory");
        __builtin_amdgcn_s_barrier();
    }

    if (j < 128) hid_out[dir * (64*128) + b * 128 + j] = hj;
}

// ---------------------------------------------------------------------------
// Batch-axis softmax (over b, 64 lanes = one wave) + weighted partial
// reduction over a 32-step s-chunk.  logits are in (S, C, B) layout.
// ---------------------------------------------------------------------------
__global__ __launch_bounds__(256)
void attn_reduce(const float* __restrict__ lt,    // (S,256,64)
                 const float* __restrict__ outs,  // (S,64,256)
                 float* __restrict__ part)        // (64 chunks,64 b,256 c)
{
    __shared__ float ltile[64 * 64];     // [c_local][b]
    __shared__ float otile[64 * 65];     // [b][c_local] padded

    const int tid  = threadIdx.x;
    const int lane = tid & 63;           // = b
    const int wv   = tid >> 6;           // wave 0..3
    const int c0   = blockIdx.x * 64;    // channel block
    const int sc   = blockIdx.y;         // s-chunk 0..63

    float acc[16];
    #pragma unroll
    for (int i = 0; i < 16; ++i) acc[i] = 0.f;

    for (int si = 0; si < 32; ++si) {
        const int s = sc * 32 + si;

        // logits tile: 4096 contiguous floats
        const float4* src = reinterpret_cast<const float4*>(
            lt + (size_t)s * 16384 + (size_t)c0 * 64);
        #pragma unroll
        for (int i = 0; i < 4; ++i)
            reinterpret_cast<float4*>(ltile)[tid + i * 256] = src[tid + i * 256];

        // out_state tile (64 b x 64 c), coalesced along c
        #pragma unroll
        for (int i = 0; i < 4; ++i) {
            int idx = tid + i * 256;
            int bb = idx >> 4, c4 = (idx & 15) * 4;
            float4 v = *reinterpret_cast<const float4*>(
                &outs[((size_t)s * 64 + bb) * 256 + c0 + c4]);
            otile[bb*65 + c4+0] = v.x; otile[bb*65 + c4+1] = v.y;
            otile[bb*65 + c4+2] = v.z; otile[bb*65 + c4+3] = v.w;
        }
        __syncthreads();

        #pragma unroll
        for (int ci = 0; ci < 16; ++ci) {
            int c = wv * 16 + ci;
            float x = ltile[c * 64 + lane];
            float m = x;
            #pragma unroll
            for (int off = 32; off; off >>= 1)
                m = fmaxf(m, __shfl_xor(m, off));
            float e = __expf(x - m);
            float ssum = e;
            #pragma unroll
            for (int off = 32; off; off >>= 1)
                ssum += __shfl_xor(ssum, off);
            float attn = e / ssum;
            acc[ci] += attn * otile[lane * 65 + c];
        }
        __syncthreads();
    }

    #pragma unroll
    for (int ci = 0; ci < 16; ++ci) {
        int c = wv * 16 + ci;
        part[(size_t)sc * 16384 + (size_t)lane * 256 + c0 + c] = acc[ci];
    }
}

__global__ __launch_bounds__(256)
void reduce_part(const float* __restrict__ part, float* __restrict__ sent)
{
    int idx = blockIdx.x * 256 + threadIdx.x;   // 0..16383 = b*256+c
    float s = 0.f;
    for (int sc = 0; sc < 64; ++sc)
        s += part[(size_t)sc * 16384 + idx];
    sent[idx] = s;
}

// ---------------------------------------------------------------------------
extern "C" void kernel_launch(void* const* d_in, const int* in_sizes, int n_in,
                              void* d_out, int out_size, void* d_ws, size_t ws_size,
                              hipStream_t stream)
{
    const float* inp    = (const float*)d_in[0];
    const float* hid0   = (const float*)d_in[1];
    const float* w_ih_f = (const float*)d_in[2];
    const float* w_hh_f = (const float*)d_in[3];
    const float* b_ih_f = (const float*)d_in[4];
    const float* b_hh_f = (const float*)d_in[5];
    const float* w_ih_b = (const float*)d_in[6];
    const float* w_hh_b = (const float*)d_in[7];
    const float* b_ih_b = (const float*)d_in[8];
    const float* b_hh_b = (const float*)d_in[9];
    const float* attn_w = (const float*)d_in[10];
    const float* attn_b = (const float*)d_in[11];
    const float* comb_w = (const float*)d_in[12];

    float* out = (float*)d_out;   // [0,16384): sent, [16384,32768): hid_out

    char* ws = (char*)d_ws;
    const size_t XG_BYTES = (size_t)S_LEN * BATCH * 384 * 4;  // 201,326,592
    const size_t OS_BYTES = (size_t)S_LEN * BATCH * 256 * 4;  // 134,217,728
    if (ws_size < 2 * XG_BYTES + OS_BYTES) return;  // need 512 MiB scratch

    float* xg_f   = (float*)(ws);
    float* xg_b   = (float*)(ws + XG_BYTES);
    float* outs   = (float*)(ws + 2 * XG_BYTES);
    float* sa     = (float*)(ws);               // reuse xg_f (dead after scan)
    float* logits = (float*)(ws + XG_BYTES);    // reuse xg_b
    float* part   = (float*)(ws);               // reuse sa (dead after K4)

    const int M = S_LEN * BATCH;                // 131072
    dim3 blk(256);

    // K1: input-side gates, both directions
    gemm_nt<0><<<dim3(6, 2048), blk, 0, stream>>>(inp, w_ih_f, b_ih_f, xg_f, M, 384, 256);
    gemm_nt<0><<<dim3(6, 2048), blk, 0, stream>>>(inp, w_ih_b, b_ih_b, xg_b, M, 384, 256);

    // K2: sequential bidirectional GRU (128 independent WGs)
    gru_scan<<<dim3(128), dim3(384), 0, stream>>>(
        xg_f, xg_b, w_hh_f, w_hh_b, b_hh_f, b_hh_b, hid0, outs, out + 16384);

    // K3: sent_annotation = out_state @ attn_w^T + attn_b
    gemm_nt<0><<<dim3(4, 2048), blk, 0, stream>>>(outs, attn_w, attn_b, sa, M, 256, 256);

    // K4: logits = sa @ comb_w^T, stored transposed (S,C,B)
    gemm_nt<1><<<dim3(4, 2048), blk, 0, stream>>>(sa, comb_w, nullptr, logits, M, 256, 256);

    // K5: softmax over batch + weighted partial sum over s-chunks
    attn_reduce<<<dim3(4, 64), blk, 0, stream>>>(logits, outs, part);

    // K6: final reduction over s-chunks -> sent
    reduce_part<<<dim3(64), blk, 0, stream>>>(part, out);
}